// Round 2
// baseline (649.224 us; speedup 1.0000x reference)
//
#include <hip/hip_runtime.h>
#include <stdint.h>

#define NN 100000
#define NE 1600000
#define FDIM 128
#define NGRAPH 128
#define ODIM 16
#define SCAN_BLK 256
#define NB_SCAN ((NN + SCAN_BLK - 1) / SCAN_BLK)   // 391

typedef __attribute__((ext_vector_type(8))) short short8;
typedef __attribute__((ext_vector_type(8))) unsigned short ushort8;
typedef __attribute__((ext_vector_type(4))) float f32x4;

__device__ __forceinline__ unsigned short f2b(float f) {
    unsigned int u = __float_as_uint(f);
    unsigned int r = (u + 0x7fffu + ((u >> 16) & 1u)) >> 16;
    return (unsigned short)r;
}

// index load honoring runtime-detected width: w=1 -> int64 storage, w=0 -> int32
__device__ __forceinline__ int ld_idx(const int* __restrict__ p, long long i, int w) {
    return w ? p[2 * i] : p[i];
}

// ---------------- detect index width ----------------
// int64 inputs (values < 2^31): odd int32 slots are all 0.
// int32 inputs: odd slots are random node ids; 64 consecutive zeros is impossible.
__global__ void k_detect(const int* __restrict__ ei, int* __restrict__ flag) {
    __shared__ int s;
    if (threadIdx.x == 0) s = 0;
    __syncthreads();
    int v = ei[2 * threadIdx.x + 1];   // odd slots 1,3,...,127
    if (v != 0) atomicOr(&s, 1);
    __syncthreads();
    if (threadIdx.x == 0) *flag = (s == 0) ? 1 : 0;
}

// ---------------- degree / dinv ----------------
__global__ void k_indeg(const int* __restrict__ ei, int* __restrict__ indeg,
                        const int* __restrict__ flag) {
    int e = blockIdx.x * 256 + threadIdx.x;
    if (e >= NE) return;
    int w = *flag;
    atomicAdd(&indeg[ld_idx(ei, (long long)NE + e, w)], 1);
}

__global__ void k_dinv(const int* __restrict__ indeg, float* __restrict__ dinv) {
    int v = blockIdx.x * 256 + threadIdx.x;
    if (v >= NN) return;
    dinv[v] = rsqrtf((float)(indeg[v] + 1));   // +1 = self loop
}

// ---------------- exclusive scan (3-phase) ----------------
__global__ void k_scan1(const int* __restrict__ in, int* __restrict__ out, int* __restrict__ bsum) {
    __shared__ int s[SCAN_BLK];
    int i = blockIdx.x * SCAN_BLK + threadIdx.x;
    int v = (i < NN) ? in[i] : 0;
    s[threadIdx.x] = v;
    __syncthreads();
    for (int o = 1; o < SCAN_BLK; o <<= 1) {
        int t = (threadIdx.x >= o) ? s[threadIdx.x - o] : 0;
        __syncthreads();
        s[threadIdx.x] += t;
        __syncthreads();
    }
    if (i < NN) out[i] = s[threadIdx.x] - v;          // exclusive
    if (threadIdx.x == SCAN_BLK - 1) bsum[blockIdx.x] = s[threadIdx.x];
}

__global__ void k_scan2(const int* __restrict__ bsum, int* __restrict__ boff) {
    __shared__ int s[512];
    int t = threadIdx.x;
    int v = (t < NB_SCAN) ? bsum[t] : 0;
    s[t] = v;
    __syncthreads();
    for (int o = 1; o < 512; o <<= 1) {
        int tv = (t >= o) ? s[t - o] : 0;
        __syncthreads();
        s[t] += tv;
        __syncthreads();
    }
    boff[t] = s[t] - v;   // exclusive block offsets
}

__global__ void k_scan3(int* __restrict__ out, const int* __restrict__ boff) {
    int i = blockIdx.x * SCAN_BLK + threadIdx.x;
    if (i < NN) out[i] += boff[blockIdx.x];
}

// ---------------- CSR build ----------------
__global__ void k_cursor(int* __restrict__ offs, int* __restrict__ cursor) {
    int v = blockIdx.x * 256 + threadIdx.x;
    if (v >= NN) return;
    cursor[v] = offs[v];
    if (v == 0) offs[NN] = NE;
}

__global__ void k_csr(const int* __restrict__ ei, int* __restrict__ cursor,
                      int* __restrict__ csr, const int* __restrict__ flag) {
    int e = blockIdx.x * 256 + threadIdx.x;
    if (e >= NE) return;
    int w = *flag;
    int s = ld_idx(ei, e, w);
    int d = ld_idx(ei, (long long)NE + e, w);
    int p = atomicAdd(&cursor[d], 1);
    csr[p] = s;
}

// ---------------- graph start offsets (batch is sorted) ----------------
__global__ void k_starts(const int* __restrict__ batch, int* __restrict__ gstart,
                         const int* __restrict__ flag) {
    int i = blockIdx.x * 256 + threadIdx.x;
    if (i >= NN) return;
    int w = *flag;
    int b = ld_idx(batch, i, w);
    int prev = (i == 0) ? -1 : ld_idx(batch, i - 1, w);
    for (int g = prev + 1; g <= b; ++g) gstart[g] = i;
    if (i == NN - 1)
        for (int g = b + 1; g <= NGRAPH; ++g) gstart[g] = NN;
}

// ---------------- w transpose+convert (fp32 -> bf16), tiny ----------------
__global__ void k_transpose(const float* __restrict__ w, unsigned short* __restrict__ wt) {
    int idx = blockIdx.x * 256 + threadIdx.x;   // 16384
    int k = idx >> 7, j = idx & 127;
    wt[j * 128 + k] = f2b(w[k * 128 + j]);
}

// ---------------- GEMM: OUT[v][:] = dinv[v] * (X[v][:] @ W)  (fp32 in/out, bf16 MFMA) ----
#define LWS 136   // padded LDS row stride (bf16 elems); 272B row, 16B aligned
__global__ void __launch_bounds__(256) k_gemm(
    const float* __restrict__ X,            // [NN,128] fp32
    const unsigned short* __restrict__ WT,  // [128,128] bf16, WT[j][k] = W[k][j]
    const float* __restrict__ dinv,
    float* __restrict__ OUT)                // [NN,128] fp32, scaled by dinv[row]
{
    __shared__ unsigned short lw[128 * LWS];
    int tid = threadIdx.x;
    for (int it = 0; it < 8; ++it) {
        int vidx = it * 256 + tid;      // 0..2047 vectors of 8
        int j = vidx >> 4;              // 0..127
        int kc = vidx & 15;             // 8-elem chunk
        ushort8 v = *(const ushort8*)(WT + j * 128 + kc * 8);
        *(ushort8*)(&lw[j * LWS + kc * 8]) = v;
    }
    __syncthreads();

    int wave = tid >> 6, lane = tid & 63;
    int quad = lane >> 4, n16 = lane & 15;
    int row0 = (blockIdx.x * 4 + wave) * 16;
    if (row0 >= NN) return;            // NN % 16 == 0

    f32x4 acc[8];
    for (int ct = 0; ct < 8; ++ct) acc[ct] = (f32x4){0.f, 0.f, 0.f, 0.f};

    const int arow = row0 + n16;
    for (int kk = 0; kk < 4; ++kk) {
        const float* ap = X + (size_t)arow * 128 + kk * 32 + quad * 8;
        float4 a01 = *(const float4*)(ap);
        float4 a23 = *(const float4*)(ap + 4);
        short8 a;
        a[0] = (short)f2b(a01.x); a[1] = (short)f2b(a01.y);
        a[2] = (short)f2b(a01.z); a[3] = (short)f2b(a01.w);
        a[4] = (short)f2b(a23.x); a[5] = (short)f2b(a23.y);
        a[6] = (short)f2b(a23.z); a[7] = (short)f2b(a23.w);
        for (int ct = 0; ct < 8; ++ct) {
            short8 b = *(const short8*)(&lw[(ct * 16 + n16) * LWS + kk * 32 + quad * 8]);
            acc[ct] = __builtin_amdgcn_mfma_f32_16x16x32_bf16(a, b, acc[ct], 0, 0, 0);
        }
    }
    // C/D layout: col = lane&15, row = quad*4 + reg
    for (int r = 0; r < 4; ++r) {
        int row = row0 + quad * 4 + r;
        float dv = dinv[row];
        for (int ct = 0; ct < 8; ++ct)
            OUT[(size_t)row * 128 + ct * 16 + n16] = acc[ct][r] * dv;
    }
}

// ---------------- aggregation (gather via CSR), bias + relu (all fp32) ----------------
__global__ void __launch_bounds__(256) k_agg(
    const float* __restrict__ XWS,     // [NN,128] fp32, rows pre-scaled by dinv[row]
    const int* __restrict__ csr,
    const int* __restrict__ offs,      // NN+1
    const float* __restrict__ dinv,
    const float* __restrict__ bias,    // 128 fp32
    float* __restrict__ H)             // [NN,128] fp32
{
    int wave = threadIdx.x >> 6, lane = threadIdx.x & 63;
    int v = blockIdx.x * 4 + wave;
    if (v >= NN) return;
    int beg = offs[v], end = offs[v + 1];
    float2 self = *(const float2*)(XWS + (size_t)v * FDIM + 2 * lane);  // self loop
    float a0 = self.x, a1 = self.y;
    int j = beg;
    for (; j + 4 <= end; j += 4) {
        int s0 = csr[j], s1 = csr[j + 1], s2 = csr[j + 2], s3 = csr[j + 3];
        float2 q0 = *(const float2*)(XWS + (size_t)s0 * FDIM + 2 * lane);
        float2 q1 = *(const float2*)(XWS + (size_t)s1 * FDIM + 2 * lane);
        float2 q2 = *(const float2*)(XWS + (size_t)s2 * FDIM + 2 * lane);
        float2 q3 = *(const float2*)(XWS + (size_t)s3 * FDIM + 2 * lane);
        a0 += q0.x + q1.x + q2.x + q3.x;
        a1 += q0.y + q1.y + q2.y + q3.y;
    }
    for (; j < end; ++j) {
        float2 q = *(const float2*)(XWS + (size_t)csr[j] * FDIM + 2 * lane);
        a0 += q.x; a1 += q.y;
    }
    float dv = dinv[v];
    float2 bp = *(const float2*)(bias + 2 * lane);
    float2 r;
    r.x = fmaxf(fmaf(a0, dv, bp.x), 0.f);
    r.y = fmaxf(fmaf(a1, dv, bp.y), 0.f);
    *(float2*)(H + (size_t)v * FDIM + 2 * lane) = r;
}

// ---------------- global mean pool (per-graph block) ----------------
__global__ void __launch_bounds__(256) k_pool(
    const float* __restrict__ H, const int* __restrict__ gstart,
    float* __restrict__ pooled)
{
    __shared__ float red[512];
    int g = blockIdx.x;
    int t = threadIdx.x;
    int pair = t & 63;   // features 2*pair, 2*pair+1
    int seg = t >> 6;    // 0..3 node strip
    int beg = gstart[g], end = gstart[g + 1];
    float a0 = 0.f, a1 = 0.f;
    for (int i = beg + seg; i < end; i += 4) {
        float2 q = *(const float2*)(H + (size_t)i * FDIM + 2 * pair);
        a0 += q.x; a1 += q.y;
    }
    red[t] = a0; red[256 + t] = a1;
    __syncthreads();
    if (seg == 0) {
        a0 = red[t] + red[t + 64] + red[t + 128] + red[t + 192];
        a1 = red[256 + t] + red[256 + t + 64] + red[256 + t + 128] + red[256 + t + 192];
        float inv = 1.f / fmaxf((float)(end - beg), 1.f);
        pooled[g * FDIM + 2 * pair]     = a0 * inv;
        pooled[g * FDIM + 2 * pair + 1] = a1 * inv;
    }
}

// ---------------- classifier (fp32) ----------------
__global__ void k_cls(const float* __restrict__ pooled, const float* __restrict__ wc,
                      const float* __restrict__ bcb, float* __restrict__ out)
{
    int idx = blockIdx.x * 256 + threadIdx.x;
    if (idx >= NGRAPH * ODIM) return;
    int g = idx >> 4, o = idx & 15;
    float acc = bcb[o];
    for (int f = 0; f < FDIM; ++f)
        acc += pooled[g * FDIM + f] * wc[f * ODIM + o];
    out[idx] = acc;
}

extern "C" void kernel_launch(void* const* d_in, const int* in_sizes, int n_in,
                              void* d_out, int out_size, void* d_ws, size_t ws_size,
                              hipStream_t stream) {
    const float* x   = (const float*)d_in[0];
    const int* ei    = (const int*)d_in[1];
    const int* batch = (const int*)d_in[2];
    const float* w1  = (const float*)d_in[3];
    const float* b1  = (const float*)d_in[4];
    const float* w2  = (const float*)d_in[5];
    const float* b2  = (const float*)d_in[6];
    const float* wc  = (const float*)d_in[7];
    const float* bc  = (const float*)d_in[8];
    float* out = (float*)d_out;

    char* ws = (char*)d_ws;
    size_t off = 0;
    auto alloc = [&](size_t bytes) -> void* {
        off = (off + 255) & ~(size_t)255;
        void* p = ws + off;
        off += bytes;
        return p;
    };
    int*   flag    = (int*)alloc(4);
    float* dinv    = (float*)alloc(NN * 4);
    int*   indeg   = (int*)alloc(NN * 4);
    int*   offs    = (int*)alloc((NN + 1) * 4);
    int*   cursor  = (int*)alloc(NN * 4);
    int*   bsum    = (int*)alloc(NB_SCAN * 4);
    int*   boff    = (int*)alloc(512 * 4);
    int*   gstart  = (int*)alloc((NGRAPH + 1) * 4);
    int*   csr     = (int*)alloc((size_t)NE * 4);
    unsigned short* wt = (unsigned short*)alloc(128 * 128 * 2);
    float* pooled  = (float*)alloc(NGRAPH * FDIM * 4);
    float* xws     = (float*)alloc((size_t)NN * FDIM * 4);
    float* h       = (float*)alloc((size_t)NN * FDIM * 4);

    k_detect<<<1, 64, 0, stream>>>(ei, flag);
    hipMemsetAsync(indeg, 0, NN * 4, stream);
    k_indeg<<<(NE + 255) / 256, 256, 0, stream>>>(ei, indeg, flag);
    k_dinv<<<(NN + 255) / 256, 256, 0, stream>>>(indeg, dinv);
    k_scan1<<<NB_SCAN, SCAN_BLK, 0, stream>>>(indeg, offs, bsum);
    k_scan2<<<1, 512, 0, stream>>>(bsum, boff);
    k_scan3<<<NB_SCAN, SCAN_BLK, 0, stream>>>(offs, boff);
    k_cursor<<<(NN + 255) / 256, 256, 0, stream>>>(offs, cursor);
    k_csr<<<(NE + 255) / 256, 256, 0, stream>>>(ei, cursor, csr, flag);
    k_starts<<<(NN + 255) / 256, 256, 0, stream>>>(batch, gstart, flag);

    // layer 1
    k_transpose<<<64, 256, 0, stream>>>(w1, wt);
    k_gemm<<<(NN / 16 + 3) / 4, 256, 0, stream>>>(x, wt, dinv, xws);
    k_agg<<<NN / 4, 256, 0, stream>>>(xws, csr, offs, dinv, b1, h);
    // layer 2
    k_transpose<<<64, 256, 0, stream>>>(w2, wt);
    k_gemm<<<(NN / 16 + 3) / 4, 256, 0, stream>>>(h, wt, dinv, xws);
    k_agg<<<NN / 4, 256, 0, stream>>>(xws, csr, offs, dinv, b2, h);
    // pool + classify
    k_pool<<<NGRAPH, 256, 0, stream>>>(h, gstart, pooled);
    k_cls<<<8, 256, 0, stream>>>(pooled, wc, bc, out);
}

// Round 3
// 402.530 us; speedup vs baseline: 1.6129x; 1.6129x over previous
//
#include <hip/hip_runtime.h>
#include <stdint.h>

#define NN 100000
#define NE 1600000
#define FDIM 128
#define NGRAPH 128
#define ODIM 16
#define NBKT ((NN + 255) / 256)        // 391 dst-buckets of 256 nodes
#define CHUNK 8192                     // edges per k_scat block
#define NSCAT ((NE + CHUNK - 1) / CHUNK)  // 196
#define BCAP 6144                      // max records per bucket (avg 4096, sigma 64)

typedef __attribute__((ext_vector_type(8))) short short8;
typedef __attribute__((ext_vector_type(8))) unsigned short ushort8;
typedef __attribute__((ext_vector_type(4))) float f32x4;

__device__ __forceinline__ float blo(unsigned int p) { return __uint_as_float(p << 16); }
__device__ __forceinline__ float bhi(unsigned int p) { return __uint_as_float(p & 0xffff0000u); }
__device__ __forceinline__ unsigned short f2b(float f) {
    unsigned int u = __float_as_uint(f);
    unsigned int r = (u + 0x7fffu + ((u >> 16) & 1u)) >> 16;
    return (unsigned short)r;
}

// index load honoring runtime-detected width: w=1 -> int64 storage, w=0 -> int32
__device__ __forceinline__ int ld_idx(const int* __restrict__ p, long long i, int w) {
    return w ? p[2 * i] : p[i];
}

// ---------------- detect index width ----------------
__global__ void k_detect(const int* __restrict__ ei, int* __restrict__ flag) {
    __shared__ int s;
    if (threadIdx.x == 0) s = 0;
    __syncthreads();
    int v = ei[2 * threadIdx.x + 1];   // odd slots: int64 high words are 0
    if (v != 0) atomicOr(&s, 1);
    __syncthreads();
    if (threadIdx.x == 0) *flag = (s == 0) ? 1 : 0;
}

// ---------------- pass A: coarse histogram of dst>>8 ----------------
__global__ void __launch_bounds__(256) k_hist(const int* __restrict__ ei,
                                              int* __restrict__ bhist,
                                              const int* __restrict__ flag) {
    __shared__ int h[NBKT];
    int t = threadIdx.x;
    for (int i = t; i < NBKT; i += 256) h[i] = 0;
    __syncthreads();
    int w = *flag;
    for (long long e = (long long)blockIdx.x * 256 + t; e < NE; e += (long long)gridDim.x * 256) {
        int d = ld_idx(ei, NE + e, w);
        atomicAdd(&h[d >> 8], 1);
    }
    __syncthreads();
    for (int i = t; i < NBKT; i += 256) if (h[i]) atomicAdd(&bhist[i], h[i]);
}

// ---------------- pass B: scan bucket counts ----------------
__global__ void k_bscan(const int* __restrict__ bhist, int* __restrict__ bbase,
                        int* __restrict__ bcursor) {
    __shared__ int s[512];
    int t = threadIdx.x;
    int v = (t < NBKT) ? bhist[t] : 0;
    s[t] = v;
    __syncthreads();
    for (int o = 1; o < 512; o <<= 1) {
        int tv = (t >= o) ? s[t - o] : 0;
        __syncthreads();
        s[t] += tv;
        __syncthreads();
    }
    int excl = s[t] - v;
    bbase[t] = excl;       // bbase[NBKT] == NE
    bcursor[t] = excl;
}

// ---------------- pass C: scatter packed records into bucket regions ----------------
// record = src (17 bits) | (dst & 255) << 17
__global__ void __launch_bounds__(512) k_scat(const int* __restrict__ ei,
                                              int* __restrict__ bcursor,
                                              unsigned int* __restrict__ rec,
                                              const int* __restrict__ flag) {
    __shared__ int hist[512];
    __shared__ int lbase[512];   // inclusive scan
    __shared__ int gbase[NBKT];
    __shared__ int lcur[NBKT];
    int t = threadIdx.x;
    int w = *flag;
    long long e0 = (long long)blockIdx.x * CHUNK;
    hist[t] = 0;
    __syncthreads();

    unsigned int myrec[16];
    int mymeta[16];   // bucket during phase 1; (bucket<<16)|rank after claim
    for (int j = 0; j < 16; ++j) {
        long long e = e0 + j * 512 + t;
        if (e < NE) {
            int s = ld_idx(ei, e, w);
            int d = ld_idx(ei, NE + e, w);
            int b = d >> 8;
            myrec[j] = (unsigned int)s | ((unsigned int)(d & 255) << 17);
            mymeta[j] = b;
            atomicAdd(&hist[b], 1);
        } else mymeta[j] = -1;
    }
    __syncthreads();
    int v = hist[t];
    lbase[t] = v;
    __syncthreads();
    for (int o = 1; o < 512; o <<= 1) {
        int tv = (t >= o) ? lbase[t - o] : 0;
        __syncthreads();
        lbase[t] += tv;
        __syncthreads();
    }
    if (t < NBKT) lcur[t] = lbase[t] - v;   // exclusive base
    __syncthreads();
    for (int j = 0; j < 16; ++j) {
        int b = mymeta[j];
        if (b >= 0) {
            int rank = atomicAdd(&lcur[b], 1) - (lbase[b] - hist[b]);  // 0..cnt-1
            mymeta[j] = (b << 16) | rank;
        }
    }
    __syncthreads();
    if (t < NBKT) {
        int c = hist[t];
        gbase[t] = c ? atomicAdd(&bcursor[t], c) : 0;
    }
    __syncthreads();
    for (int j = 0; j < 16; ++j) {
        int m = mymeta[j];
        if (m >= 0) rec[gbase[m >> 16] + (m & 0xffff)] = myrec[j];
    }
}

// ---------------- pass D: per-bucket counting sort -> csr + offs ----------------
__global__ void __launch_bounds__(256) k_bucket(const unsigned int* __restrict__ rec,
                                                const int* __restrict__ bbase,
                                                int* __restrict__ csr,
                                                int* __restrict__ offs) {
    __shared__ unsigned int rbuf[BCAP];
    __shared__ int srcout[BCAP];
    __shared__ int hist[256], scan[256], cur[256];
    int b = blockIdx.x, t = threadIdx.x;
    int base = bbase[b], end = bbase[b + 1];
    int cnt = end - base;
    if (cnt > BCAP) cnt = BCAP;
    hist[t] = 0;
    __syncthreads();
    for (int j = t; j < cnt; j += 256) {
        unsigned int r = rec[base + j];
        rbuf[j] = r;
        atomicAdd(&hist[r >> 17], 1);
    }
    __syncthreads();
    int v = hist[t];
    scan[t] = v;
    __syncthreads();
    for (int o = 1; o < 256; o <<= 1) {
        int tv = (t >= o) ? scan[t - o] : 0;
        __syncthreads();
        scan[t] += tv;
        __syncthreads();
    }
    int excl = scan[t] - v;
    cur[t] = excl;
    __syncthreads();
    for (int j = t; j < cnt; j += 256) {
        unsigned int r = rbuf[j];
        int p = atomicAdd(&cur[r >> 17], 1);
        srcout[p] = (int)(r & 0x1FFFFu);
    }
    __syncthreads();
    for (int j = t; j < cnt; j += 256) csr[base + j] = srcout[j];
    int node = (b << 8) + t;
    if (node < NN) offs[node] = base + excl;
    if (b == NBKT - 1 && t == 0) offs[NN] = NE;
}

// ---------------- dinv from offs ----------------
__global__ void k_dinv(const int* __restrict__ offs, float* __restrict__ dinv) {
    int v = blockIdx.x * 256 + threadIdx.x;
    if (v >= NN) return;
    dinv[v] = rsqrtf((float)(offs[v + 1] - offs[v] + 1));   // +1 = self loop
}

// ---------------- graph start offsets (batch is sorted) ----------------
__global__ void k_starts(const int* __restrict__ batch, int* __restrict__ gstart,
                         const int* __restrict__ flag) {
    int i = blockIdx.x * 256 + threadIdx.x;
    if (i >= NN) return;
    int w = *flag;
    int b = ld_idx(batch, i, w);
    int prev = (i == 0) ? -1 : ld_idx(batch, i - 1, w);
    for (int g = prev + 1; g <= b; ++g) gstart[g] = i;
    if (i == NN - 1)
        for (int g = b + 1; g <= NGRAPH; ++g) gstart[g] = NN;
}

// ---------------- w transpose+convert (fp32 -> bf16) ----------------
__global__ void k_transpose(const float* __restrict__ w, unsigned short* __restrict__ wt) {
    int idx = blockIdx.x * 256 + threadIdx.x;   // 16384
    int k = idx >> 7, j = idx & 127;
    wt[j * 128 + k] = f2b(w[k * 128 + j]);
}

// ---------------- GEMM: OUT[v][:] = bf16(dinv[v] * (X[v][:] @ W)) ----------------
#define LWS 136   // padded LDS row stride (bf16 elems)
template <bool BF16IN>
__global__ void __launch_bounds__(256) k_gemm(
    const void* __restrict__ Xv,            // [NN,128] fp32 or bf16
    const unsigned short* __restrict__ WT,  // [128,128] bf16, WT[j][k] = W[k][j]
    const float* __restrict__ dinv,
    unsigned short* __restrict__ OUT)       // [NN,128] bf16, scaled by dinv[row]
{
    __shared__ unsigned short lw[128 * LWS];
    int tid = threadIdx.x;
    for (int it = 0; it < 8; ++it) {
        int vidx = it * 256 + tid;
        int j = vidx >> 4, kc = vidx & 15;
        ushort8 v = *(const ushort8*)(WT + j * 128 + kc * 8);
        *(ushort8*)(&lw[j * LWS + kc * 8]) = v;
    }
    __syncthreads();

    int wave = tid >> 6, lane = tid & 63;
    int quad = lane >> 4, n16 = lane & 15;
    int row0 = (blockIdx.x * 4 + wave) * 16;
    if (row0 >= NN) return;   // NN % 16 == 0

    f32x4 acc[8];
    for (int ct = 0; ct < 8; ++ct) acc[ct] = (f32x4){0.f, 0.f, 0.f, 0.f};

    const int arow = row0 + n16;
    for (int kk = 0; kk < 4; ++kk) {
        short8 a;
        if (BF16IN) {
            a = *(const short8*)((const unsigned short*)Xv + (size_t)arow * 128 + kk * 32 + quad * 8);
        } else {
            const float* ap = (const float*)Xv + (size_t)arow * 128 + kk * 32 + quad * 8;
            float4 a01 = *(const float4*)(ap);
            float4 a23 = *(const float4*)(ap + 4);
            a[0] = (short)f2b(a01.x); a[1] = (short)f2b(a01.y);
            a[2] = (short)f2b(a01.z); a[3] = (short)f2b(a01.w);
            a[4] = (short)f2b(a23.x); a[5] = (short)f2b(a23.y);
            a[6] = (short)f2b(a23.z); a[7] = (short)f2b(a23.w);
        }
        for (int ct = 0; ct < 8; ++ct) {
            short8 b = *(const short8*)(&lw[(ct * 16 + n16) * LWS + kk * 32 + quad * 8]);
            acc[ct] = __builtin_amdgcn_mfma_f32_16x16x32_bf16(a, b, acc[ct], 0, 0, 0);
        }
    }
    // C/D layout: col = lane&15, row = quad*4 + reg
    for (int r = 0; r < 4; ++r) {
        int row = row0 + quad * 4 + r;
        float dv = dinv[row];
        for (int ct = 0; ct < 8; ++ct)
            OUT[(size_t)row * 128 + ct * 16 + n16] = f2b(acc[ct][r] * dv);
    }
}

// ---------------- aggregation (gather via CSR), bias + relu ----------------
__global__ void __launch_bounds__(256) k_agg(
    const unsigned short* __restrict__ XWS,   // [NN,128] bf16, pre-scaled by dinv[row]
    const int* __restrict__ csr,
    const int* __restrict__ offs,
    const float* __restrict__ dinv,
    const float* __restrict__ bias,           // 128 fp32
    unsigned short* __restrict__ H)           // [NN,128] bf16
{
    int wave = threadIdx.x >> 6, lane = threadIdx.x & 63;
    int v = blockIdx.x * 4 + wave;
    if (v >= NN) return;
    int beg = offs[v], end = offs[v + 1];
    unsigned int p = *(const unsigned int*)(XWS + (size_t)v * FDIM + 2 * lane);  // self loop
    float a0 = blo(p), a1 = bhi(p);
    int j = beg;
    for (; j + 4 <= end; j += 4) {
        int s0 = csr[j], s1 = csr[j + 1], s2 = csr[j + 2], s3 = csr[j + 3];
        unsigned int q0 = *(const unsigned int*)(XWS + (size_t)s0 * FDIM + 2 * lane);
        unsigned int q1 = *(const unsigned int*)(XWS + (size_t)s1 * FDIM + 2 * lane);
        unsigned int q2 = *(const unsigned int*)(XWS + (size_t)s2 * FDIM + 2 * lane);
        unsigned int q3 = *(const unsigned int*)(XWS + (size_t)s3 * FDIM + 2 * lane);
        a0 += blo(q0) + blo(q1) + blo(q2) + blo(q3);
        a1 += bhi(q0) + bhi(q1) + bhi(q2) + bhi(q3);
    }
    for (; j < end; ++j) {
        unsigned int q = *(const unsigned int*)(XWS + (size_t)csr[j] * FDIM + 2 * lane);
        a0 += blo(q); a1 += bhi(q);
    }
    float dv = dinv[v];
    float2 bp = *(const float2*)(bias + 2 * lane);
    float r0 = fmaxf(fmaf(a0, dv, bp.x), 0.f);
    float r1 = fmaxf(fmaf(a1, dv, bp.y), 0.f);
    *(unsigned int*)(H + (size_t)v * FDIM + 2 * lane) =
        (unsigned int)f2b(r0) | ((unsigned int)f2b(r1) << 16);
}

// ---------------- global mean pool ----------------
__global__ void __launch_bounds__(256) k_pool(
    const unsigned short* __restrict__ H, const int* __restrict__ gstart,
    float* __restrict__ pooled)
{
    __shared__ float red[512];
    int g = blockIdx.x;
    int t = threadIdx.x;
    int pair = t & 63;
    int seg = t >> 6;
    int beg = gstart[g], end = gstart[g + 1];
    float a0 = 0.f, a1 = 0.f;
    for (int i = beg + seg; i < end; i += 4) {
        unsigned int q = *(const unsigned int*)(H + (size_t)i * FDIM + 2 * pair);
        a0 += blo(q); a1 += bhi(q);
    }
    red[t] = a0; red[256 + t] = a1;
    __syncthreads();
    if (seg == 0) {
        a0 = red[t] + red[t + 64] + red[t + 128] + red[t + 192];
        a1 = red[256 + t] + red[256 + t + 64] + red[256 + t + 128] + red[256 + t + 192];
        float inv = 1.f / fmaxf((float)(end - beg), 1.f);
        pooled[g * FDIM + 2 * pair]     = a0 * inv;
        pooled[g * FDIM + 2 * pair + 1] = a1 * inv;
    }
}

// ---------------- classifier (fp32) ----------------
__global__ void k_cls(const float* __restrict__ pooled, const float* __restrict__ wc,
                      const float* __restrict__ bcb, float* __restrict__ out)
{
    int idx = blockIdx.x * 256 + threadIdx.x;
    if (idx >= NGRAPH * ODIM) return;
    int g = idx >> 4, o = idx & 15;
    float acc = bcb[o];
    for (int f = 0; f < FDIM; ++f)
        acc += pooled[g * FDIM + f] * wc[f * ODIM + o];
    out[idx] = acc;
}

extern "C" void kernel_launch(void* const* d_in, const int* in_sizes, int n_in,
                              void* d_out, int out_size, void* d_ws, size_t ws_size,
                              hipStream_t stream) {
    const float* x   = (const float*)d_in[0];
    const int* ei    = (const int*)d_in[1];
    const int* batch = (const int*)d_in[2];
    const float* w1  = (const float*)d_in[3];
    const float* b1  = (const float*)d_in[4];
    const float* w2  = (const float*)d_in[5];
    const float* b2  = (const float*)d_in[6];
    const float* wc  = (const float*)d_in[7];
    const float* bc  = (const float*)d_in[8];
    float* out = (float*)d_out;

    char* ws = (char*)d_ws;
    size_t off = 0;
    auto alloc = [&](size_t bytes) -> void* {
        off = (off + 255) & ~(size_t)255;
        void* p = ws + off;
        off += bytes;
        return p;
    };
    int*   flag    = (int*)alloc(4);
    int*   bhist   = (int*)alloc(NBKT * 4);
    int*   bbase   = (int*)alloc(512 * 4);
    int*   bcursor = (int*)alloc(512 * 4);
    int*   offs    = (int*)alloc((NN + 1) * 4);
    float* dinv    = (float*)alloc(NN * 4);
    int*   gstart  = (int*)alloc((NGRAPH + 1) * 4);
    unsigned int* rec = (unsigned int*)alloc((size_t)NE * 4);
    int*   csr     = (int*)alloc((size_t)NE * 4);
    unsigned short* wt = (unsigned short*)alloc(128 * 128 * 2);
    float* pooled  = (float*)alloc(NGRAPH * FDIM * 4);
    unsigned short* xws = (unsigned short*)alloc((size_t)NN * FDIM * 2);
    unsigned short* h   = (unsigned short*)alloc((size_t)NN * FDIM * 2);

    k_detect<<<1, 64, 0, stream>>>(ei, flag);
    hipMemsetAsync(bhist, 0, NBKT * 4, stream);
    k_hist<<<1024, 256, 0, stream>>>(ei, bhist, flag);
    k_bscan<<<1, 512, 0, stream>>>(bhist, bbase, bcursor);
    k_scat<<<NSCAT, 512, 0, stream>>>(ei, bcursor, rec, flag);
    k_bucket<<<NBKT, 256, 0, stream>>>(rec, bbase, csr, offs);
    k_dinv<<<(NN + 255) / 256, 256, 0, stream>>>(offs, dinv);
    k_starts<<<(NN + 255) / 256, 256, 0, stream>>>(batch, gstart, flag);

    // layer 1
    k_transpose<<<64, 256, 0, stream>>>(w1, wt);
    k_gemm<false><<<(NN / 16 + 3) / 4, 256, 0, stream>>>(x, wt, dinv, xws);
    k_agg<<<NN / 4, 256, 0, stream>>>(xws, csr, offs, dinv, b1, h);
    // layer 2
    k_transpose<<<64, 256, 0, stream>>>(w2, wt);
    k_gemm<true><<<(NN / 16 + 3) / 4, 256, 0, stream>>>(h, wt, dinv, xws);
    k_agg<<<NN / 4, 256, 0, stream>>>(xws, csr, offs, dinv, b2, h);
    // pool + classify
    k_pool<<<NGRAPH, 256, 0, stream>>>(h, gstart, pooled);
    k_cls<<<8, 256, 0, stream>>>(pooled, wc, bc, out);
}

// Round 4
// 365.289 us; speedup vs baseline: 1.7773x; 1.1019x over previous
//
#include <hip/hip_runtime.h>
#include <stdint.h>

#define NN 100000
#define NE 1600000
#define FDIM 128
#define NGRAPH 128
#define ODIM 16
#define NBKT 391                       // dst-buckets of 256 nodes
#define CAP 4608                       // fixed bucket capacity (mean 4092, sd 64)
#define SCHUNK 4096                    // edges per k_scat block
#define NSCAT ((NE + SCHUNK - 1) / SCHUNK)  // 391

typedef __attribute__((ext_vector_type(8))) short short8;
typedef __attribute__((ext_vector_type(8))) unsigned short ushort8;
typedef __attribute__((ext_vector_type(4))) float f32x4;

__device__ __forceinline__ float blo(unsigned int p) { return __uint_as_float(p << 16); }
__device__ __forceinline__ float bhi(unsigned int p) { return __uint_as_float(p & 0xffff0000u); }
__device__ __forceinline__ unsigned short f2b(float f) {
    unsigned int u = __float_as_uint(f);
    unsigned int r = (u + 0x7fffu + ((u >> 16) & 1u)) >> 16;
    return (unsigned short)r;
}
__device__ __forceinline__ unsigned int packbf(float lo, float hi) {
    return (unsigned int)f2b(lo) | ((unsigned int)f2b(hi) << 16);
}

// index load honoring runtime-detected width: w=1 -> int64 storage, w=0 -> int32
__device__ __forceinline__ int ld_idx(const int* __restrict__ p, long long i, int w) {
    return w ? p[2 * i] : p[i];
}

// ---------------- init: detect index width + init bucket cursors ----------------
__global__ void k_init(const int* __restrict__ ei, int* __restrict__ flag,
                       int* __restrict__ bcursor) {
    __shared__ int s;
    int t = threadIdx.x;
    if (t == 0) s = 0;
    __syncthreads();
    if (t < 64) {
        int v = ei[2 * t + 1];   // int64 inputs: odd int32 slots all 0
        if (v != 0) atomicOr(&s, 1);
    }
    if (t < NBKT) bcursor[t] = t * CAP;
    __syncthreads();
    if (t == 0) *flag = (s == 0) ? 1 : 0;
}

// ---------------- scatter edges into fixed-stride dst-buckets ----------------
// record = src (17 bits) | (dst & 255) << 17
__global__ void __launch_bounds__(512) k_scat(const int* __restrict__ ei,
                                              int* __restrict__ bcursor,
                                              unsigned int* __restrict__ rec,
                                              const int* __restrict__ flag) {
    __shared__ int hist[NBKT];
    __shared__ int gcur[NBKT];
    int t = threadIdx.x;
    for (int i = t; i < NBKT; i += 512) hist[i] = 0;
    __syncthreads();
    int w = *flag;
    long long e0 = (long long)blockIdx.x * SCHUNK;
    unsigned int myrec[8];
    int mybkt[8];
    #pragma unroll
    for (int j = 0; j < 8; ++j) {
        long long e = e0 + j * 512 + t;
        if (e < NE) {
            int s = ld_idx(ei, e, w);
            int d = ld_idx(ei, NE + e, w);
            mybkt[j] = d >> 8;
            myrec[j] = (unsigned int)s | ((unsigned int)(d & 255) << 17);
            atomicAdd(&hist[mybkt[j]], 1);
        } else mybkt[j] = -1;
    }
    __syncthreads();
    for (int i = t; i < NBKT; i += 512) {
        int c = hist[i];
        if (c) gcur[i] = atomicAdd(&bcursor[i], c);
    }
    __syncthreads();
    #pragma unroll
    for (int j = 0; j < 8; ++j) {
        int b = mybkt[j];
        if (b >= 0) {
            int p = atomicAdd(&gcur[b], 1);
            if (p < (b + 1) * CAP) rec[p] = myrec[j];   // overflow guard (~never)
        }
    }
}

// ---------------- per-bucket counting sort -> csr + offs + deg + dinv ----------------
__global__ void __launch_bounds__(256) k_bucket(const unsigned int* __restrict__ rec,
                                                const int* __restrict__ bcursor,
                                                int* __restrict__ csr,
                                                int* __restrict__ offs,
                                                int* __restrict__ deg,
                                                float* __restrict__ dinv) {
    __shared__ unsigned int rbuf[CAP];
    __shared__ int srcout[CAP];
    __shared__ int hist[256], scn[256], cur[256];
    int b = blockIdx.x, t = threadIdx.x;
    int base = b * CAP;
    int cnt = bcursor[b] - base;
    if (cnt > CAP) cnt = CAP;
    hist[t] = 0;
    __syncthreads();
    for (int j = t; j < cnt; j += 256) {
        unsigned int r = rec[base + j];
        rbuf[j] = r;
        atomicAdd(&hist[r >> 17], 1);
    }
    __syncthreads();
    int v = hist[t];
    scn[t] = v;
    __syncthreads();
    for (int o = 1; o < 256; o <<= 1) {
        int tv = (t >= o) ? scn[t - o] : 0;
        __syncthreads();
        scn[t] += tv;
        __syncthreads();
    }
    int excl = scn[t] - v;
    cur[t] = excl;
    int node = (b << 8) + t;
    if (node < NN) {
        offs[node] = base + excl;
        deg[node] = v;
        dinv[node] = rsqrtf((float)(v + 1));   // +1 = self loop
    }
    __syncthreads();
    for (int j = t; j < cnt; j += 256) {
        unsigned int r = rbuf[j];
        int p = atomicAdd(&cur[r >> 17], 1);
        srcout[p] = (int)(r & 0x1FFFFu);
    }
    __syncthreads();
    for (int j = t; j < cnt; j += 256) csr[base + j] = srcout[j];
}

// ---------------- graph start offsets (batch is sorted) ----------------
__global__ void k_starts(const int* __restrict__ batch, int* __restrict__ gstart,
                         const int* __restrict__ flag) {
    int i = blockIdx.x * 256 + threadIdx.x;
    if (i >= NN) return;
    int w = *flag;
    int b = ld_idx(batch, i, w);
    int prev = (i == 0) ? -1 : ld_idx(batch, i - 1, w);
    for (int g = prev + 1; g <= b; ++g) gstart[g] = i;
    if (i == NN - 1)
        for (int g = b + 1; g <= NGRAPH; ++g) gstart[g] = NN;
}

// ---------------- both weight transposes (fp32 -> bf16) ----------------
__global__ void k_transpose(const float* __restrict__ w1, const float* __restrict__ w2,
                            unsigned short* __restrict__ wt1, unsigned short* __restrict__ wt2) {
    int idx = blockIdx.x * 256 + threadIdx.x;   // 32768
    int which = idx >> 14, r = idx & 16383;
    int k = r >> 7, j = r & 127;
    const float* w = which ? w2 : w1;
    unsigned short* wt = which ? wt2 : wt1;
    wt[j * 128 + k] = f2b(w[k * 128 + j]);
}

// ---------------- GEMM: OUT[v][:] = bf16(dinv[v] * (X[v][:] @ W)) ----------------
#define LWS 136   // padded LDS row stride (bf16 elems)
template <bool BF16IN>
__global__ void __launch_bounds__(256) k_gemm(
    const void* __restrict__ Xv,            // [NN,128] fp32 or bf16
    const unsigned short* __restrict__ WT,  // [128,128] bf16, WT[j][k] = W[k][j]
    const float* __restrict__ dinv,
    unsigned short* __restrict__ OUT)       // [NN,128] bf16, scaled by dinv[row]
{
    __shared__ unsigned short lw[128 * LWS];
    int tid = threadIdx.x;
    for (int it = 0; it < 8; ++it) {
        int vidx = it * 256 + tid;
        int j = vidx >> 4, kc = vidx & 15;
        ushort8 v = *(const ushort8*)(WT + j * 128 + kc * 8);
        *(ushort8*)(&lw[j * LWS + kc * 8]) = v;
    }
    __syncthreads();

    int wave = tid >> 6, lane = tid & 63;
    int quad = lane >> 4, n16 = lane & 15;
    int row0 = (blockIdx.x * 4 + wave) * 16;
    if (row0 >= NN) return;   // NN % 16 == 0

    f32x4 acc[8];
    for (int ct = 0; ct < 8; ++ct) acc[ct] = (f32x4){0.f, 0.f, 0.f, 0.f};

    const int arow = row0 + n16;
    for (int kk = 0; kk < 4; ++kk) {
        short8 a;
        if (BF16IN) {
            a = *(const short8*)((const unsigned short*)Xv + (size_t)arow * 128 + kk * 32 + quad * 8);
        } else {
            const float* ap = (const float*)Xv + (size_t)arow * 128 + kk * 32 + quad * 8;
            float4 a01 = *(const float4*)(ap);
            float4 a23 = *(const float4*)(ap + 4);
            a[0] = (short)f2b(a01.x); a[1] = (short)f2b(a01.y);
            a[2] = (short)f2b(a01.z); a[3] = (short)f2b(a01.w);
            a[4] = (short)f2b(a23.x); a[5] = (short)f2b(a23.y);
            a[6] = (short)f2b(a23.z); a[7] = (short)f2b(a23.w);
        }
        for (int ct = 0; ct < 8; ++ct) {
            short8 b = *(const short8*)(&lw[(ct * 16 + n16) * LWS + kk * 32 + quad * 8]);
            acc[ct] = __builtin_amdgcn_mfma_f32_16x16x32_bf16(a, b, acc[ct], 0, 0, 0);
        }
    }
    // C/D layout: col = lane&15, row = quad*4 + reg
    for (int r = 0; r < 4; ++r) {
        int row = row0 + quad * 4 + r;
        float dv = dinv[row];
        for (int ct = 0; ct < 8; ++ct)
            OUT[(size_t)row * 128 + ct * 16 + n16] = f2b(acc[ct][r] * dv);
    }
}

// ---------------- aggregation: 4 edges per dwordx4, xor-shuffle reduce ----------------
__global__ void __launch_bounds__(256) k_agg(
    const unsigned short* __restrict__ XWS,   // [NN,128] bf16, pre-scaled by dinv[row]
    const int* __restrict__ csr,
    const int* __restrict__ offs,
    const int* __restrict__ deg,
    const float* __restrict__ dinv,
    const float* __restrict__ bias,           // 128 fp32
    unsigned short* __restrict__ H)           // [NN,128] bf16
{
    int wave = threadIdx.x >> 6, lane = threadIdx.x & 63;
    int v = blockIdx.x * 4 + wave;             // NN % 4 == 0
    int g = lane >> 4, f = lane & 15;          // edge slot, feature chunk (8 feats)
    int beg = offs[v], end = beg + deg[v];
    float a[8];
    if (g == 0) {   // self loop
        uint4 q = *(const uint4*)(XWS + (size_t)v * FDIM + f * 8);
        a[0] = blo(q.x); a[1] = bhi(q.x); a[2] = blo(q.y); a[3] = bhi(q.y);
        a[4] = blo(q.z); a[5] = bhi(q.z); a[6] = blo(q.w); a[7] = bhi(q.w);
    } else {
        #pragma unroll
        for (int i = 0; i < 8; ++i) a[i] = 0.f;
    }
    int j = beg;
    for (; j + 4 <= end; j += 4) {
        int idx = csr[j + g];
        uint4 q = *(const uint4*)(XWS + (size_t)idx * FDIM + f * 8);
        a[0] += blo(q.x); a[1] += bhi(q.x); a[2] += blo(q.y); a[3] += bhi(q.y);
        a[4] += blo(q.z); a[5] += bhi(q.z); a[6] += blo(q.w); a[7] += bhi(q.w);
    }
    int rem = end - j;
    if (g < rem) {
        int idx = csr[j + g];
        uint4 q = *(const uint4*)(XWS + (size_t)idx * FDIM + f * 8);
        a[0] += blo(q.x); a[1] += bhi(q.x); a[2] += blo(q.y); a[3] += bhi(q.y);
        a[4] += blo(q.z); a[5] += bhi(q.z); a[6] += blo(q.w); a[7] += bhi(q.w);
    }
    #pragma unroll
    for (int i = 0; i < 8; ++i) {
        a[i] += __shfl_xor(a[i], 16);
        a[i] += __shfl_xor(a[i], 32);
    }
    if (g == 0) {
        float dv = dinv[v];
        float4 b0 = *(const float4*)(bias + f * 8);
        float4 b1 = *(const float4*)(bias + f * 8 + 4);
        uint4 o;
        o.x = packbf(fmaxf(fmaf(a[0], dv, b0.x), 0.f), fmaxf(fmaf(a[1], dv, b0.y), 0.f));
        o.y = packbf(fmaxf(fmaf(a[2], dv, b0.z), 0.f), fmaxf(fmaf(a[3], dv, b0.w), 0.f));
        o.z = packbf(fmaxf(fmaf(a[4], dv, b1.x), 0.f), fmaxf(fmaf(a[5], dv, b1.y), 0.f));
        o.w = packbf(fmaxf(fmaf(a[6], dv, b1.z), 0.f), fmaxf(fmaf(a[7], dv, b1.w), 0.f));
        *(uint4*)(H + (size_t)v * FDIM + f * 8) = o;
    }
}

// ---------------- global mean pool ----------------
__global__ void __launch_bounds__(256) k_pool(
    const unsigned short* __restrict__ H, const int* __restrict__ gstart,
    float* __restrict__ pooled)
{
    __shared__ float red[512];
    int g = blockIdx.x;
    int t = threadIdx.x;
    int pair = t & 63;
    int seg = t >> 6;
    int beg = gstart[g], end = gstart[g + 1];
    float a0 = 0.f, a1 = 0.f;
    for (int i = beg + seg; i < end; i += 4) {
        unsigned int q = *(const unsigned int*)(H + (size_t)i * FDIM + 2 * pair);
        a0 += blo(q); a1 += bhi(q);
    }
    red[t] = a0; red[256 + t] = a1;
    __syncthreads();
    if (seg == 0) {
        a0 = red[t] + red[t + 64] + red[t + 128] + red[t + 192];
        a1 = red[256 + t] + red[256 + t + 64] + red[256 + t + 128] + red[256 + t + 192];
        float inv = 1.f / fmaxf((float)(end - beg), 1.f);
        pooled[g * FDIM + 2 * pair]     = a0 * inv;
        pooled[g * FDIM + 2 * pair + 1] = a1 * inv;
    }
}

// ---------------- classifier (fp32) ----------------
__global__ void k_cls(const float* __restrict__ pooled, const float* __restrict__ wc,
                      const float* __restrict__ bcb, float* __restrict__ out)
{
    int idx = blockIdx.x * 256 + threadIdx.x;
    if (idx >= NGRAPH * ODIM) return;
    int g = idx >> 4, o = idx & 15;
    float acc = bcb[o];
    for (int f = 0; f < FDIM; ++f)
        acc += pooled[g * FDIM + f] * wc[f * ODIM + o];
    out[idx] = acc;
}

extern "C" void kernel_launch(void* const* d_in, const int* in_sizes, int n_in,
                              void* d_out, int out_size, void* d_ws, size_t ws_size,
                              hipStream_t stream) {
    const float* x   = (const float*)d_in[0];
    const int* ei    = (const int*)d_in[1];
    const int* batch = (const int*)d_in[2];
    const float* w1  = (const float*)d_in[3];
    const float* b1  = (const float*)d_in[4];
    const float* w2  = (const float*)d_in[5];
    const float* b2  = (const float*)d_in[6];
    const float* wc  = (const float*)d_in[7];
    const float* bc  = (const float*)d_in[8];
    float* out = (float*)d_out;

    char* ws = (char*)d_ws;
    size_t off = 0;
    auto alloc = [&](size_t bytes) -> void* {
        off = (off + 255) & ~(size_t)255;
        void* p = ws + off;
        off += bytes;
        return p;
    };
    int*   flag    = (int*)alloc(4);
    int*   bcursor = (int*)alloc(NBKT * 4);
    int*   offs    = (int*)alloc(NN * 4);
    int*   deg     = (int*)alloc(NN * 4);
    float* dinv    = (float*)alloc(NN * 4);
    int*   gstart  = (int*)alloc((NGRAPH + 1) * 4);
    unsigned int* rec = (unsigned int*)alloc((size_t)NBKT * CAP * 4);
    int*   csr     = (int*)alloc((size_t)NBKT * CAP * 4);
    unsigned short* wt1 = (unsigned short*)alloc(128 * 128 * 2);
    unsigned short* wt2 = (unsigned short*)alloc(128 * 128 * 2);
    float* pooled  = (float*)alloc(NGRAPH * FDIM * 4);
    unsigned short* xws = (unsigned short*)alloc((size_t)NN * FDIM * 2);
    unsigned short* h   = (unsigned short*)alloc((size_t)NN * FDIM * 2);

    k_init<<<1, 512, 0, stream>>>(ei, flag, bcursor);
    k_scat<<<NSCAT, 512, 0, stream>>>(ei, bcursor, rec, flag);
    k_bucket<<<NBKT, 256, 0, stream>>>(rec, bcursor, csr, offs, deg, dinv);
    k_starts<<<(NN + 255) / 256, 256, 0, stream>>>(batch, gstart, flag);
    k_transpose<<<128, 256, 0, stream>>>(w1, w2, wt1, wt2);

    // layer 1
    k_gemm<false><<<(NN / 16 + 3) / 4, 256, 0, stream>>>(x, wt1, dinv, xws);
    k_agg<<<NN / 4, 256, 0, stream>>>(xws, csr, offs, deg, dinv, b1, h);
    // layer 2
    k_gemm<true><<<(NN / 16 + 3) / 4, 256, 0, stream>>>(h, wt2, dinv, xws);
    k_agg<<<NN / 4, 256, 0, stream>>>(xws, csr, offs, deg, dinv, b2, h);
    // pool + classify
    k_pool<<<NGRAPH, 256, 0, stream>>>(h, gstart, pooled);
    k_cls<<<8, 256, 0, stream>>>(pooled, wc, bc, out);
}